// Round 2
// baseline (360.341 us; speedup 1.0000x reference)
//
#include <hip/hip_runtime.h>

// Problem constants (from reference)
#define NN 50000
#define EE 800000
#define KIN 512
#define HF 256      // H*OUT
#define NH 8
#define FOUT 32
#define NC 16
#define NEG 0.2f
#define NB_SCAN 196  // ceil(NN/256)

typedef unsigned short u16;
typedef __attribute__((ext_vector_type(8))) short shortx8;   // 8 bf16 (4 VGPRs) MFMA A/B frag
typedef __attribute__((ext_vector_type(4))) float floatx4;   // MFMA C/D frag
typedef __attribute__((ext_vector_type(8))) unsigned short ushortx8;
typedef __attribute__((ext_vector_type(4))) unsigned uintx4;

__device__ __forceinline__ float lrelu(float x) { return x > 0.f ? x : NEG * x; }

__device__ __forceinline__ u16 f2bf(float f) {
    unsigned u = __float_as_uint(f);
    return (u16)((u + 0x7FFFu + ((u >> 16) & 1u)) >> 16);   // RNE
}
__device__ __forceinline__ float bf2f(u16 v) {
    return __uint_as_float((unsigned)v << 16);
}
// pack two fp32 -> (bf16(a) | bf16(b)<<16), round-half-up (bias 2^-25, negligible)
__device__ __forceinline__ unsigned pk2bf(float a, float b) {
    unsigned ua = __float_as_uint(a), ub = __float_as_uint(b);
    return ((ua + 0x8000u) >> 16) | ((ub + 0x8000u) & 0xffff0000u);
}

__device__ __forceinline__ void gll16(const void* g, void* l) {
    // async global->LDS, 16B/lane; LDS dest = wave-uniform base + lane*16
    __builtin_amdgcn_global_load_lds((const __attribute__((address_space(1))) void*)g,
                                     (__attribute__((address_space(3))) void*)l, 16, 0, 0);
}

// ---------------- CSR count + weight converts (merged kernel) ----------------
__global__ void count_deg_convw(const int* __restrict__ dst, int* __restrict__ deg,
                                const float* __restrict__ W1, const float* __restrict__ W2,
                                u16* __restrict__ w1t, u16* __restrict__ w2t) {
    int e = blockIdx.x * 256 + threadIdx.x;
    if (e < EE) atomicAdd(&deg[dst[e]], 1);
    if (e < KIN * HF) {                        // W1 [512,256] -> w1t [256,512] bf16
        int k = e >> 8, n = e & 255;
        w1t[n * KIN + k] = f2bf(W1[e]);
    } else if (e < KIN * HF + HF * NC) {       // W2 [256,16] -> w2t [16,256] bf16
        int e2 = e - KIN * HF;
        int k = e2 >> 4, c = e2 & 15;
        w2t[c * HF + k] = f2bf(W2[e2]);
    }
}

__global__ __launch_bounds__(256) void scan_a(const int* __restrict__ deg, int* __restrict__ bsum) {
    __shared__ int sm[256];
    int t = threadIdx.x;
    int i = blockIdx.x * 256 + t;
    sm[t] = (i < NN) ? deg[i] : 0;
    __syncthreads();
    for (int o = 128; o; o >>= 1) { if (t < o) sm[t] += sm[t + o]; __syncthreads(); }
    if (t == 0) bsum[blockIdx.x] = sm[0];
}

// per-block scan; block offset derived in-kernel from bsum (scan_b merged away)
__global__ __launch_bounds__(256) void scan_c(const int* __restrict__ deg, const int* __restrict__ bsum,
                                              int* __restrict__ off) {
    __shared__ int sm[256];
    __shared__ int pre[256];
    int t = threadIdx.x;
    // block-prefix: sum of bsum[0..blockIdx-1]
    pre[t] = (t < blockIdx.x && t < NB_SCAN) ? bsum[t] : 0;
    __syncthreads();
    for (int o = 128; o; o >>= 1) { if (t < o) pre[t] += pre[t + o]; __syncthreads(); }
    int bofs = pre[0];
    __syncthreads();
    int i = blockIdx.x * 256 + t;
    int d = (i < NN) ? deg[i] : 0;
    sm[t] = d;
    __syncthreads();
    for (int dd = 1; dd < 256; dd <<= 1) {
        int v = (t >= dd) ? sm[t - dd] : 0;
        __syncthreads();
        sm[t] += v;
        __syncthreads();
    }
    if (i < NN) off[i] = bofs + sm[t] - d;
    if (i == 0) off[NN] = EE;
}

__global__ void fill_csr(const int* __restrict__ src, const int* __restrict__ dst,
                         const int* __restrict__ off, int* __restrict__ cursor,
                         int* __restrict__ csr_src) {
    int e = blockIdx.x * 256 + threadIdx.x;
    if (e < EE) {
        int d = dst[e];
        int pos = atomicAdd(&cursor[d], 1);
        csr_src[off[d] + pos] = src[e];
    }
}

// ---------------- GEMM1 (bf16 MFMA, fused x-convert + fused scores) ----------------
// h1b[N,256] = bf16(x)[N,512] @ W1T^T ; es1/ed1[n*8+h] (interleaved) from fp32 acc in epilogue.
// Tile 128x256 (full width). 4 waves, each 64 rows x 128 cols = 4x8 MFMA tiles.
__global__ __launch_bounds__(256, 2) void gemm1_mfma(const float* __restrict__ x,
                                                     const u16* __restrict__ w1t,
                                                     u16* __restrict__ h1b,
                                                     const float* __restrict__ a1s,
                                                     const float* __restrict__ a1d,
                                                     float* __restrict__ es1,
                                                     float* __restrict__ ed1) {
    __shared__ __align__(16) float As[128 * 32];   // [row][k] fp32, 16 KB
    __shared__ __align__(16) u16 Bs[256 * 32];     // [col][k] bf16, 16 KB
    int t = threadIdx.x;
    int lane = t & 63, wave = t >> 6;
    int wm = wave >> 1, wn = wave & 1;
    int lm = lane & 15, quad = lane >> 4;
    int bm = blockIdx.x * 128;

    floatx4 acc[4][8];
#pragma unroll
    for (int i = 0; i < 4; i++)
#pragma unroll
        for (int j = 0; j < 8; j++) acc[i][j] = (floatx4){0.f, 0.f, 0.f, 0.f};

    // A staging: wave covers rows wave*32..+31 ; 4 insts x 8 rows (fp32, 4 floats/lane)
    int arow_l = wave * 32 + (lane >> 3);
    int akoff = (lane & 7) * 4;
    const float* aptr[4];
#pragma unroll
    for (int i = 0; i < 4; i++) {
        int ar = bm + arow_l + i * 8;
        if (ar > NN - 1) ar = NN - 1;     // tail dup-reads; writes guarded
        aptr[i] = x + (size_t)ar * KIN + akoff;
    }
    float* alds[4];
#pragma unroll
    for (int i = 0; i < 4; i++) alds[i] = As + (wave * 32 + i * 8) * 32;

    // B staging: wave covers cols wave*64..+63 ; 4 insts x 16 rows (bf16, 8 elems/lane)
    int brow_l = wave * 64 + (lane >> 2);
    int bkoff = (lane & 3) * 8;
    const u16* bptr[4];
#pragma unroll
    for (int i = 0; i < 4; i++) bptr[i] = w1t + (size_t)(brow_l + i * 16) * KIN + bkoff;
    u16* blds[4];
#pragma unroll
    for (int i = 0; i < 4; i++) blds[i] = Bs + (wave * 64 + i * 16) * 32;

    int offA[4], offB[8];
#pragma unroll
    for (int i = 0; i < 4; i++) offA[i] = (wm * 64 + i * 16 + lm) * 32 + quad * 8;
#pragma unroll
    for (int j = 0; j < 8; j++) offB[j] = (wn * 128 + j * 16 + lm) * 32 + quad * 8;

    for (int kk = 0; kk < KIN; kk += 32) {
#pragma unroll
        for (int i = 0; i < 4; i++) gll16(aptr[i] + kk, alds[i]);
#pragma unroll
        for (int i = 0; i < 4; i++) gll16(bptr[i] + kk, blds[i]);
        __syncthreads();
        shortx8 af[4], bf[8];
#pragma unroll
        for (int i = 0; i < 4; i++) {
            const float4* ap = (const float4*)&As[offA[i]];
            float4 lo = ap[0], hi = ap[1];
            union { uintx4 u; shortx8 s; } cv;
            cv.u[0] = pk2bf(lo.x, lo.y);
            cv.u[1] = pk2bf(lo.z, lo.w);
            cv.u[2] = pk2bf(hi.x, hi.y);
            cv.u[3] = pk2bf(hi.z, hi.w);
            af[i] = cv.s;
        }
#pragma unroll
        for (int j = 0; j < 8; j++) bf[j] = *(const shortx8*)&Bs[offB[j]];
#pragma unroll
        for (int i = 0; i < 4; i++)
#pragma unroll
            for (int j = 0; j < 8; j++)
                acc[i][j] = __builtin_amdgcn_mfma_f32_16x16x32_bf16(af[i], bf[j], acc[i][j], 0, 0, 0);
        __syncthreads();
    }

    // epilogue 1: h1 store. C/D map col=lane&15, row=quad*4+reg -> bf16
#pragma unroll
    for (int i = 0; i < 4; i++) {
        int row = bm + wm * 64 + i * 16 + quad * 4;
#pragma unroll
        for (int j = 0; j < 8; j++) {
            int col = wn * 128 + j * 16 + lm;
#pragma unroll
            for (int r = 0; r < 4; r++) {
                if (row + r < NN) h1b[(size_t)(row + r) * HF + col] = f2bf(acc[i][j][r]);
            }
        }
    }

    // epilogue 2: fused per-node scores, interleaved es1/ed1[n*8+h].
    // Head h' within this wn half covers cols j=2h',2h'+1.
    float as_v[8], ad_v[8];
#pragma unroll
    for (int j = 0; j < 8; j++) {
        int col = wn * 128 + j * 16 + lm;
        as_v[j] = a1s[col];
        ad_v[j] = a1d[col];
    }
#pragma unroll
    for (int i = 0; i < 4; i++) {
#pragma unroll
        for (int r = 0; r < 4; r++) {
            int row = bm + wm * 64 + i * 16 + quad * 4 + r;
#pragma unroll
            for (int hp = 0; hp < 4; hp++) {
                float e_s = acc[i][2 * hp][r] * as_v[2 * hp] + acc[i][2 * hp + 1][r] * as_v[2 * hp + 1];
                float e_d = acc[i][2 * hp][r] * ad_v[2 * hp] + acc[i][2 * hp + 1][r] * ad_v[2 * hp + 1];
#pragma unroll
                for (int o = 8; o; o >>= 1) {
                    e_s += __shfl_down(e_s, o, 16);
                    e_d += __shfl_down(e_d, o, 16);
                }
                if (lm == 0 && row < NN) {
                    int h = wn * 4 + hp;
                    es1[row * NH + h] = e_s;
                    ed1[row * NH + h] = e_d;
                }
            }
        }
    }
}

// ---------------- layer-1 softmax aggregate (+ ELU), MFMA formulation ----------------
// Block = 16 dst nodes (CSR-contiguous edges). Per 32-edge chunk:
//   Out[16x256] += P[16x32] @ H[32x256],  P[m][k] = p_k if dst_local(k)==m else 0.
// H rows gathered async into LDS via global_load_lds (per-lane global src, XOR-swizzled
// 16B-chunk so column-wise B-frag reads are bank-conflict-free). Softmax denominator via
// one extra MFMA against an all-ones B fragment (C/D rows align with the output tile).
// Wave w handles heads 2w,2w+1 (feat cols w*64..w*64+63). No max-subtraction (as before).
// NOTE: all __shfl calls are OUTSIDE divergent branches (shfl from an exec-inactive
// source lane is undefined — this was the round-1 correctness bug).
__global__ __launch_bounds__(256) void agg1_mfma(const u16* __restrict__ h1b, const float* __restrict__ es,
                                                 const float* __restrict__ ed, const int* __restrict__ off,
                                                 const int* __restrict__ csr_src, u16* __restrict__ out1b) {
    __shared__ __align__(16) u16 Hs[32 * 256];          // 16 KB staged rows (swizzled 16B chunks)
    __shared__ __align__(16) u16 pTs[8][32];            // p (bf16) per head x edge-slot
    __shared__ __align__(16) unsigned char dstloc[32];  // local dst node of each edge-slot
    __shared__ int offs_s[17];
    __shared__ float ed_s[16][8];

    int t = threadIdx.x;
    int lane = t & 63, wave = t >> 6;
    int lm = lane & 15, quad = lane >> 4;
    int base = blockIdx.x * 16;

    if (t < 17) offs_s[t] = off[base + t];
    if (t < 128) ed_s[t >> 3][t & 7] = ed[(base + (t >> 3)) * NH + (t & 7)];
    int e0 = off[base];
    int e1 = off[base + 16];
    int nch = (e1 - e0 + 31) >> 5;
    __syncthreads();

    floatx4 acc[2][2];     // [head-in-pair][16-col half]
    floatx4 accS[2];       // ones-columns: softmax denominators
#pragma unroll
    for (int a = 0; a < 2; a++) {
        accS[a] = (floatx4){0.f, 0.f, 0.f, 0.f};
#pragma unroll
        for (int b = 0; b < 2; b++) acc[a][b] = (floatx4){0.f, 0.f, 0.f, 0.f};
    }

    int h0 = 2 * wave;
    shortx8 ones;
#pragma unroll
    for (int i = 0; i < 8; i++) ones[i] = (short)0x3F80;  // bf16 1.0

    int k_p = t >> 3, h_p = t & 7;          // p-compute role: edge-slot, head
    // prefetch chunk-0 edge sources
    int sv = 0;
    if (nch > 0) {
        int g = e0 + (lane & 31);
        sv = csr_src[g < e1 ? g : e1 - 1];
    }

    for (int c = 0; c < nch; c++) {
        // prefetch next chunk's sources (consumed next iteration)
        int svn = 0;
        if (c + 1 < nch) {
            int g = e0 + ((c + 1) << 5) + (lane & 31);
            svn = csr_src[g < e1 ? g : e1 - 1];
        }
        // stage 32 rows: wave covers rows pass*8 + 2*wave + (lane>>5); src 16B-chunk XOR-swizzled
#pragma unroll
        for (int pass = 0; pass < 4; pass++) {
            int r = pass * 8 + 2 * wave + (lane >> 5);
            int s = __shfl(sv, r, 64);
            const u16* sp = h1b + (size_t)s * HF + (((lane & 31) ^ (pass << 1)) << 3);
            gll16(sp, Hs + pass * 2048 + wave * 512);
        }
        // p-compute: 256 threads = 32 edge-slots x 8 heads
        {
            int g = e0 + (c << 5) + k_p;
            int s = __shfl(sv, k_p, 64);    // UNCONDITIONAL: shfl must not sit in a divergent branch
            float pv = 0.f;
            if (g < e1) {
                int m = 0;
                if (offs_s[m + 8] <= g) m += 8;
                if (offs_s[m + 4] <= g) m += 4;
                if (offs_s[m + 2] <= g) m += 2;
                if (offs_s[m + 1] <= g) m += 1;
                float lg = es[s * NH + h_p] + ed_s[m][h_p];
                lg = lg > 0.f ? lg : NEG * lg;
                pv = __expf(lg);
                if (h_p == 0) dstloc[k_p] = (unsigned char)m;
            }
            pTs[h_p][k_p] = f2bf(pv);
        }
        __syncthreads();   // drains gll16 + LDS writes

        // A-frags: p masked by (dst_local == lm); k = quad*8+j
        union { uintx4 u; shortx8 s; } pa, pb, a0, a1;
        pa.s = *(const shortx8*)&pTs[h0][quad * 8];
        pb.s = *(const shortx8*)&pTs[h0 + 1][quad * 8];
        unsigned dw0 = *(const unsigned*)&dstloc[quad * 8];
        unsigned dw1 = *(const unsigned*)&dstloc[quad * 8 + 4];
        unsigned ulm = (unsigned)lm;
        unsigned mm0 = ((dw0 & 255u) == ulm ? 0xffffu : 0u) | (((dw0 >> 8) & 255u) == ulm ? 0xffff0000u : 0u);
        unsigned mm1 = (((dw0 >> 16) & 255u) == ulm ? 0xffffu : 0u) | ((dw0 >> 24) == ulm ? 0xffff0000u : 0u);
        unsigned mm2 = ((dw1 & 255u) == ulm ? 0xffffu : 0u) | (((dw1 >> 8) & 255u) == ulm ? 0xffff0000u : 0u);
        unsigned mm3 = (((dw1 >> 16) & 255u) == ulm ? 0xffffu : 0u) | ((dw1 >> 24) == ulm ? 0xffff0000u : 0u);
        a0.u[0] = pa.u[0] & mm0; a0.u[1] = pa.u[1] & mm1; a0.u[2] = pa.u[2] & mm2; a0.u[3] = pa.u[3] & mm3;
        a1.u[0] = pb.u[0] & mm0; a1.u[1] = pb.u[1] & mm1; a1.u[2] = pb.u[2] & mm2; a1.u[3] = pb.u[3] & mm3;

        // denominators (ones-B)
        accS[0] = __builtin_amdgcn_mfma_f32_16x16x32_bf16(a0.s, ones, accS[0], 0, 0, 0);
        accS[1] = __builtin_amdgcn_mfma_f32_16x16x32_bf16(a1.s, ones, accS[1], 0, 0, 0);

        // 4 feat tiles: B[k][n] = Hs[k][fbase+lm] (swizzle-corrected column reads)
#pragma unroll
        for (int hh = 0; hh < 2; hh++) {
#pragma unroll
            for (int half = 0; half < 2; half++) {
                int f = (h0 + hh) * 32 + half * 16 + lm;
                int bidx = (quad * 8) * 256 + (((f >> 3) ^ (quad << 1)) << 3) + (f & 7);
                shortx8 bfv;
#pragma unroll
                for (int j = 0; j < 8; j++) bfv[j] = (short)Hs[bidx + j * 256];
                acc[hh][half] = __builtin_amdgcn_mfma_f32_16x16x32_bf16(
                    hh ? a1.s : a0.s, bfv, acc[hh][half], 0, 0, 0);
            }
        }
        __syncthreads();   // Hs/pTs free for next chunk
        sv = svn;
    }

    // epilogue: normalize, ELU, bf16 store. C/D: col=lane&15, row=quad*4+reg.
#pragma unroll
    for (int hh = 0; hh < 2; hh++) {
#pragma unroll
        for (int r = 0; r < 4; r++) {
            float sden = accS[hh][r];
            float inv = sden > 0.f ? 1.0f / sden : 0.f;
            int n = base + quad * 4 + r;
#pragma unroll
            for (int half = 0; half < 2; half++) {
                float v = acc[hh][half][r] * inv;
                v = v > 0.f ? v : (__expf(v) - 1.0f);
                out1b[(size_t)n * HF + (h0 + hh) * 32 + half * 16 + lm] = f2bf(v);
            }
        }
    }
}

// ---------------- GEMM2 (1-wave MFMA) + layer-2 scores; h2 stored bf16 ----------------
__global__ __launch_bounds__(64) void gemm2_mfma(const u16* __restrict__ out1b, const u16* __restrict__ w2t,
                                                 const float* __restrict__ a2s, const float* __restrict__ a2d,
                                                 u16* __restrict__ h2b, float* __restrict__ es2,
                                                 float* __restrict__ ed2) {
    int lane = threadIdx.x;
    int lm = lane & 15, quad = lane >> 4;
    int nb = blockIdx.x * 16;
    floatx4 acc = (floatx4){0.f, 0.f, 0.f, 0.f};
    const u16* arow = out1b + (size_t)(nb + lm) * HF + quad * 8;
    const u16* brow = w2t + lm * HF + quad * 8;
#pragma unroll
    for (int kk = 0; kk < HF; kk += 32) {
        shortx8 af = *(const shortx8*)(arow + kk);
        shortx8 bf = *(const shortx8*)(brow + kk);
        acc = __builtin_amdgcn_mfma_f32_16x16x32_bf16(af, bf, acc, 0, 0, 0);
    }
    float a2sc = a2s[lm], a2dc = a2d[lm];
#pragma unroll
    for (int r = 0; r < 4; r++) {
        int n = nb + quad * 4 + r;
        float v = acc[r];
        h2b[n * NC + lm] = f2bf(v);
        float ps = v * a2sc, pd = v * a2dc;
#pragma unroll
        for (int o = 8; o; o >>= 1) {
            ps += __shfl_down(ps, o, 16);
            pd += __shfl_down(pd, o, 16);
        }
        if (lm == 0) { es2[n] = ps; ed2[n] = pd; }
    }
}

// ---------------- layer-2 aggregate + log_softmax: 16 nodes x 16 classes ----------------
__global__ __launch_bounds__(256) void agg2(const u16* __restrict__ h2b, const float* __restrict__ es2,
                                            const float* __restrict__ ed2, const int* __restrict__ off,
                                            const int* __restrict__ csr_src, float* __restrict__ out) {
    int t = threadIdx.x;
    int nid = blockIdx.x * 16 + (t >> 4);   // NN % 16 == 0
    int c = t & 15;
    int beg = off[nid];
    int deg = off[nid + 1] - beg;
    float edn = ed2[nid];
    float s = 0.f, acc = 0.f;
    for (int base = 0; base < deg; base += 16) {
        int nch = deg - base; if (nch > 16) nch = 16;
        int sv = 0;
        if (c < nch) sv = csr_src[beg + base + c];
        int sva[16];
#pragma unroll
        for (int e = 0; e < 16; e++) sva[e] = __shfl(sv, e, 16);
        float hva[16];
#pragma unroll
        for (int e = 0; e < 16; e++) hva[e] = bf2f(h2b[sva[e] * NC + c]);  // e>=nch: row 0, masked by p=0
        float p = 0.f;
        if (c < nch) p = __expf(lrelu(es2[sv] + edn));
        s += p;
        float pa[16];
#pragma unroll
        for (int e = 0; e < 16; e++) pa[e] = __shfl(p, e, 16);
#pragma unroll
        for (int e = 0; e < 16; e++) acc += pa[e] * hva[e];
    }
#pragma unroll
    for (int o = 8; o; o >>= 1) s += __shfl_down(s, o, 16);
    s = __shfl(s, 0, 16);
    float v = (s > 0.f) ? acc / s : 0.f;
    float m2 = v;
#pragma unroll
    for (int o = 8; o; o >>= 1) m2 = fmaxf(m2, __shfl_down(m2, o, 16));
    m2 = __shfl(m2, 0, 16);
    float se = __expf(v - m2);
#pragma unroll
    for (int o = 8; o; o >>= 1) se += __shfl_down(se, o, 16);
    se = __shfl(se, 0, 16);
    out[nid * NC + c] = v - m2 - __logf(se);
}

extern "C" void kernel_launch(void* const* d_in, const int* in_sizes, int n_in,
                              void* d_out, int out_size, void* d_ws, size_t ws_size,
                              hipStream_t stream) {
    const float* x   = (const float*)d_in[0];
    const float* W1  = (const float*)d_in[1];
    const float* a1s = (const float*)d_in[2];
    const float* a1d = (const float*)d_in[3];
    const float* W2  = (const float*)d_in[4];
    const float* a2s = (const float*)d_in[5];
    const float* a2d = (const float*)d_in[6];
    const int*   ei  = (const int*)d_in[7];
    const int* srcv = ei;
    const int* dstv = ei + EE;
    float* out = (float*)d_out;

    // workspace (~62 MB)
    u16* h1b    = (u16*)d_ws;                         // N*256 bf16
    u16* out1b  = h1b + (size_t)NN * HF;              // N*256 bf16
    float* es1  = (float*)(out1b + (size_t)NN * HF);  // N*8 interleaved
    float* ed1  = es1 + (size_t)NN * NH;              // N*8
    u16* h2b    = (u16*)(ed1 + (size_t)NN * NH);      // N*16 bf16
    float* es2v = (float*)(h2b + (size_t)NN * NC);    // N
    float* ed2v = es2v + NN;                          // N
    int* deg    = (int*)(ed2v + NN);                  // N   (deg+cursor contiguous: one memset)
    int* cursor = deg + NN;                           // N
    int* offs   = cursor + NN;                        // N+1
    int* csr    = offs + NN + 1;                      // E
    int* bsum   = csr + EE;                           // 256
    u16* w1t    = (u16*)(bsum + 256);                 // 256*512 bf16
    u16* w2t    = w1t + (size_t)HF * KIN;             // 16*256 bf16

    hipMemsetAsync(deg, 0, 2 * NN * sizeof(int), stream);
    count_deg_convw<<<(EE + 255) / 256, 256, 0, stream>>>(dstv, deg, W1, W2, w1t, w2t);
    scan_a<<<NB_SCAN, 256, 0, stream>>>(deg, bsum);
    scan_c<<<NB_SCAN, 256, 0, stream>>>(deg, bsum, offs);
    fill_csr<<<(EE + 255) / 256, 256, 0, stream>>>(srcv, dstv, offs, cursor, csr);
    gemm1_mfma<<<(NN + 127) / 128, 256, 0, stream>>>(x, w1t, h1b, a1s, a1d, es1, ed1);
    agg1_mfma<<<NN / 16, 256, 0, stream>>>(h1b, es1, ed1, offs, csr, out1b);
    gemm2_mfma<<<NN / 16, 64, 0, stream>>>(out1b, w2t, a2s, a2d, h2b, es2v, ed2v);
    agg2<<<NN / 16, 256, 0, stream>>>(h2b, es2v, ed2v, offs, csr, out);
}